// Round 1
// baseline (934.457 us; speedup 1.0000x reference)
//
#include <hip/hip_runtime.h>
#include <stdint.h>

#define FEAT 256
#define CODES 8192
#define NQ 16384                 // 16*32*32
#define ZQ_ELEMS (NQ * FEAT)     // 4194304
#define TM 128
#define TN 128
#define KCH 16
#define KSPLIT 4

// ---------------------------------------------------------------------------
// numpy-pairwise replication: sum of squares of a 256-length fp32 vector in
// EXACTLY numpy's pairwise_sum order (two 128-halves, each with 8 sequential
// accumulators combined ((r0+r1)+(r2+r3))+((r4+r5)+(r6+r7)), halves lo+hi).
// One 16-lane group per vector: lane16 = h*8 + j, accumulator j of half h.
// __fmul_rn/__fadd_rn block FMA contraction (must match np's separate ops).
// ---------------------------------------------------------------------------
template <int STRIDE>
__device__ __forceinline__ float pairwise256_sq(const float* __restrict__ base, int lane16) {
  const int h = lane16 >> 3, j = lane16 & 7;
  const float* p = base + (h * 128 + j) * STRIDE;
  float x = p[0];
  float r = __fmul_rn(x, x);
#pragma unroll
  for (int i = 1; i < 16; ++i) {
    float y = p[i * 8 * STRIDE];
    r = __fadd_rn(r, __fmul_rn(y, y));
  }
  // tree combine across the 8 accumulators (exact: a+b rounds same as b+a)
  r = __fadd_rn(r, __shfl_xor(r, 1, 64));
  r = __fadd_rn(r, __shfl_xor(r, 2, 64));
  r = __fadd_rn(r, __shfl_xor(r, 4, 64));
  // halves: res = pairwise(first 128) + pairwise(second 128)
  float other = __shfl_xor(r, 8, 64);
  float lo = (h == 0) ? r : other;
  float hi = (h == 0) ? other : r;
  return __fadd_rn(lo, hi);
}

// cbnorm[k] = sum_c cb[k][c]^2 (np order); znorm[q] = sum_c zf[q][c]^2 (np order)
// z layout is [B][C][H][W] -> zf[q][c] strided by 1024 floats.
__global__ __launch_bounds__(256) void norms_kernel(const float* __restrict__ cb,
                                                    const float* __restrict__ z,
                                                    float* __restrict__ cbnorm,
                                                    float* __restrict__ znorm) {
  const int g = (blockIdx.x * 256 + threadIdx.x) >> 4;  // global 16-lane group
  const int lane16 = threadIdx.x & 15;
  if (g < CODES) {
    float v = pairwise256_sq<1>(cb + g * FEAT, lane16);
    if (lane16 == 0) cbnorm[g] = v;
  } else {
    const int q = g - CODES;  // 0..NQ-1
    const int b = q >> 10, hw = q & 1023;
    float v = pairwise256_sq<1024>(z + b * (FEAT * 1024) + hw, lane16);
    if (lane16 == 0) znorm[q] = v;
  }
}

// ---------------------------------------------------------------------------
// Fused distance GEMM + argmin. 256 threads, TM x TN = 128x128 tile, 8x8 per
// thread, KC=16 LDS staging over C. K split KSPLIT ways across blocks; global
// combine via atomicMin on (sortable_score<<32 | idx) keys (ties -> min idx,
// matching np.argmin first-occurrence).
// ---------------------------------------------------------------------------
__global__ __launch_bounds__(256, 2) void vq_main(const float* __restrict__ z,
                                                  const float* __restrict__ cb,
                                                  const float* __restrict__ cbnorm,
                                                  const float* __restrict__ znorm,
                                                  unsigned long long* __restrict__ packed) {
  __shared__ __align__(16) float Zs[KCH][TM];
  __shared__ __align__(16) float Cs[KCH][TN + 4];  // +4: staging stores 2-way, keeps 16B align
  __shared__ float RV[TM][17];
  __shared__ int RI[TM][17];

  const int tid = threadIdx.x;
  const int tx = tid & 15, ty = tid >> 4;
  const int mtile = blockIdx.x >> 2;   // 0..127
  const int ks = blockIdx.x & (KSPLIT - 1);
  const int m0 = mtile * TM;
  const int bb = m0 >> 10;             // batch (tile never crosses b: 1024 % 128 == 0)
  const int hw0 = m0 & 1023;
  const float* zbase = z + bb * (FEAT * 1024) + hw0;

  float bestv[8];
  int besti[8];
#pragma unroll
  for (int i = 0; i < 8; ++i) { bestv[i] = 3.4e38f; besti[i] = 0; }

  const int kbeg = ks * (CODES / KSPLIT);

  for (int kc = 0; kc < (CODES / KSPLIT) / TN; ++kc) {
    const int k0 = kbeg + kc * TN;
    float acc[8][8];
#pragma unroll
    for (int i = 0; i < 8; ++i)
#pragma unroll
      for (int j = 0; j < 8; ++j) acc[i][j] = 0.f;

    for (int c0 = 0; c0 < FEAT; c0 += KCH) {
      __syncthreads();
      // stage Z: Zs[cc][m], global rows contiguous in m -> coalesced float4
#pragma unroll
      for (int r = 0; r < 2; ++r) {
        int f = tid + r * 256;
        int cc = f >> 5, m4 = (f & 31) << 2;
        *(float4*)&Zs[cc][m4] = *(const float4*)(zbase + (c0 + cc) * 1024 + m4);
      }
      // stage C (transpose): cb rows contiguous in c -> float4 load, scatter store
#pragma unroll
      for (int r = 0; r < 2; ++r) {
        int f = tid + r * 256;
        int nn = f >> 2, c4 = (f & 3) << 2;
        float4 v = *(const float4*)(cb + (k0 + nn) * FEAT + c0 + c4);
        Cs[c4 + 0][nn] = v.x;
        Cs[c4 + 1][nn] = v.y;
        Cs[c4 + 2][nn] = v.z;
        Cs[c4 + 3][nn] = v.w;
      }
      __syncthreads();
#pragma unroll
      for (int cc = 0; cc < KCH; ++cc) {
        float4 z0 = *(const float4*)&Zs[cc][ty * 8];
        float4 z1 = *(const float4*)&Zs[cc][ty * 8 + 4];
        float4 ca = *(const float4*)&Cs[cc][tx * 8];
        float4 cbv = *(const float4*)&Cs[cc][tx * 8 + 4];
        float zr[8] = {z0.x, z0.y, z0.z, z0.w, z1.x, z1.y, z1.z, z1.w};
        float cr[8] = {ca.x, ca.y, ca.z, ca.w, cbv.x, cbv.y, cbv.z, cbv.w};
#pragma unroll
        for (int i = 0; i < 8; ++i)
#pragma unroll
          for (int j = 0; j < 8; ++j) acc[i][j] = __builtin_fmaf(zr[i], cr[j], acc[i][j]);
      }
    }
    // score + running argmin. Replicate np rounding: ((-2*dot) + |z|^2) + |cb|^2
#pragma unroll
    for (int j = 0; j < 8; ++j) {
      const int k = k0 + tx * 8 + j;
      const float cn = cbnorm[k];
#pragma unroll
      for (int i = 0; i < 8; ++i) {
        const float zni = znorm[m0 + ty * 8 + i];
        float t1 = __fmul_rn(-2.0f, acc[i][j]);
        float s = __fadd_rn(__fadd_rn(t1, zni), cn);
        if (s < bestv[i]) { bestv[i] = s; besti[i] = k; }  // strict <: keeps smallest k
      }
    }
  }

  // cross-thread reduction: 16 tx-candidates per query row
#pragma unroll
  for (int i = 0; i < 8; ++i) {
    RV[ty * 8 + i][tx] = bestv[i];
    RI[ty * 8 + i][tx] = besti[i];
  }
  __syncthreads();
  if (tid < TM) {
    float bv = RV[tid][0];
    int bi = RI[tid][0];
#pragma unroll
    for (int t = 1; t < 16; ++t) {
      float v = RV[tid][t];
      int ii = RI[tid][t];
      if (v < bv || (v == bv && ii < bi)) { bv = v; bi = ii; }
    }
    unsigned u = __float_as_uint(bv);
    u = (u & 0x80000000u) ? ~u : (u | 0x80000000u);  // monotonic float->uint
    unsigned long long key = ((unsigned long long)u << 32) | (unsigned)bi;
    atomicMin(&packed[m0 + tid], key);
  }
}

// gather: zq[b][c][hw] = cb[idx[q]][c]; idx as float appended after zq
__global__ __launch_bounds__(256) void vq_gather(const float* __restrict__ cb,
                                                 const unsigned long long* __restrict__ packed,
                                                 float* __restrict__ out) {
  const int q0 = blockIdx.x * 64;
  const int nl = threadIdx.x & 63;
  const int cg = threadIdx.x >> 6;
  const int q = q0 + nl;
  const int kq = (int)(unsigned)packed[q];  // low 32 bits = idx
  const int b = q >> 10, hw = q & 1023;
  const float4* cb4 = (const float4*)cb;
#pragma unroll
  for (int t = 0; t < 16; ++t) {
    int cc = cg + t * 4;                       // float4 group of c
    float4 v = cb4[kq * 64 + cc];
    int base = b * (FEAT * 1024) + (cc * 4) * 1024 + hw;  // lanes: consecutive hw -> coalesced
    out[base] = v.x;
    out[base + 1024] = v.y;
    out[base + 2048] = v.z;
    out[base + 3072] = v.w;
  }
  if (threadIdx.x < 64) {
    out[ZQ_ELEMS + q0 + threadIdx.x] = (float)(unsigned)packed[q0 + threadIdx.x];
  }
}

extern "C" void kernel_launch(void* const* d_in, const int* in_sizes, int n_in,
                              void* d_out, int out_size, void* d_ws, size_t ws_size,
                              hipStream_t stream) {
  const float* z = (const float*)d_in[0];
  const float* cb = (const float*)d_in[1];
  // ws layout: cbnorm[8192] f32 | znorm[16384] f32 | packed[16384] u64  (= 224 KB)
  float* cbnorm = (float*)d_ws;
  float* znorm = cbnorm + CODES;
  unsigned long long* packed = (unsigned long long*)(znorm + NQ);

  hipMemsetAsync(packed, 0xFF, NQ * sizeof(unsigned long long), stream);
  norms_kernel<<<(CODES + NQ) / 16, 256, 0, stream>>>(cb, z, cbnorm, znorm);
  vq_main<<<(NQ / TM) * KSPLIT, 256, 0, stream>>>(z, cb, cbnorm, znorm, packed);
  vq_gather<<<NQ / 64, 256, 0, stream>>>(cb, packed, (float*)d_out);
}

// Round 2
// 564.559 us; speedup vs baseline: 1.6552x; 1.6552x over previous
//
#include <hip/hip_runtime.h>
#include <stdint.h>

#define FEAT 256
#define CODES 8192
#define NQ 16384                 // 16*32*32
#define ZQ_ELEMS (NQ * FEAT)
#define MARGIN 5e-3f

typedef _Float16 f16x8 __attribute__((ext_vector_type(8)));
typedef float f32x4 __attribute__((ext_vector_type(4)));

// global -> LDS direct DMA, 16B per lane. LDS dst = uniform base + lane*16.
__device__ __forceinline__ void async_lds16(void* lds, const void* g) {
  __builtin_amdgcn_global_load_lds(
      (const __attribute__((address_space(1))) void*)(uintptr_t)(g),
      (__attribute__((address_space(3))) void*)(uint32_t)(uintptr_t)(lds),
      16, 0, 0);
}

// ---------------------------------------------------------------------------
// numpy pairwise sum-of-squares replication (unchanged from R1 — passed).
// ---------------------------------------------------------------------------
template <int STRIDE>
__device__ __forceinline__ float pairwise256_sq(const float* __restrict__ base, int lane16) {
  const int h = lane16 >> 3, j = lane16 & 7;
  const float* p = base + (h * 128 + j) * STRIDE;
  float x = p[0];
  float r = __fmul_rn(x, x);
#pragma unroll
  for (int i = 1; i < 16; ++i) {
    float y = p[i * 8 * STRIDE];
    r = __fadd_rn(r, __fmul_rn(y, y));
  }
  r = __fadd_rn(r, __shfl_xor(r, 1, 64));
  r = __fadd_rn(r, __shfl_xor(r, 2, 64));
  r = __fadd_rn(r, __shfl_xor(r, 4, 64));
  float other = __shfl_xor(r, 8, 64);
  float lo = (h == 0) ? r : other;
  float hi = (h == 0) ? other : r;
  return __fadd_rn(lo, hi);
}

__global__ __launch_bounds__(256) void norms_kernel(const float* __restrict__ cb,
                                                    const float* __restrict__ z,
                                                    float* __restrict__ cbnorm,
                                                    float* __restrict__ znorm) {
  const int g = (blockIdx.x * 256 + threadIdx.x) >> 4;
  const int lane16 = threadIdx.x & 15;
  if (g < CODES) {
    float v = pairwise256_sq<1>(cb + g * FEAT, lane16);
    if (lane16 == 0) cbnorm[g] = v;
  } else {
    const int q = g - CODES;
    const int b = q >> 10, hw = q & 1023;
    float v = pairwise256_sq<1024>(z + b * (FEAT * 1024) + hw, lane16);
    if (lane16 == 0) znorm[q] = v;
  }
}

// ---------------------------------------------------------------------------
// convA: z [B][C][H][W] fp32 -> Atile[mt][ct][r 128][c 32] fp16 (plain layout)
// ---------------------------------------------------------------------------
__global__ __launch_bounds__(256) void convA(const float* __restrict__ z, char* __restrict__ At) {
  __shared__ _Float16 T[128 * 40];  // [q 128][c 32] pad to 40
  const int t = threadIdx.x;
  const int mt = blockIdx.x >> 3, ct = blockIdx.x & 7;
  const int q0 = mt * 128, bb = q0 >> 10, hw0 = q0 & 1023;
  const int c0 = ct * 32;
#pragma unroll
  for (int it = 0; it < 16; ++it) {
    const int cc = it * 2 + (t >> 7);
    const int qi = t & 127;
    float v = z[bb * (FEAT * 1024) + (c0 + cc) * 1024 + hw0 + qi];
    T[qi * 40 + cc] = (_Float16)v;
  }
  __syncthreads();
  const int r = t >> 1, h = t & 1;
  float4 a = *(const float4*)&T[r * 40 + h * 16];
  float4 b = *(const float4*)&T[r * 40 + h * 16 + 8];
  char* dst = At + (size_t)(mt * 8 + ct) * 8192 + t * 32;
  *(float4*)dst = a;
  *(float4*)(dst + 16) = b;
}

// ---------------------------------------------------------------------------
// convB: cb [K][C] fp32 -> Btile[nt][ct][n 128][c 32] fp16, scaled by 256
// ---------------------------------------------------------------------------
__global__ __launch_bounds__(256) void convB(const float* __restrict__ cb, char* __restrict__ Bt) {
  const int t = threadIdx.x;
  const int nt = blockIdx.x >> 3, ct = blockIdx.x & 7;
  const int n = t >> 1, h = t & 1;
  const float* src = cb + (size_t)(nt * 128 + n) * FEAT + ct * 32 + h * 16;
  f16x8 o0, o1;
#pragma unroll
  for (int e = 0; e < 8; ++e) o0[e] = (_Float16)(src[e] * 256.0f);
#pragma unroll
  for (int e = 0; e < 8; ++e) o1[e] = (_Float16)(src[8 + e] * 256.0f);
  char* dst = Bt + (size_t)(nt * 8 + ct) * 8192 + t * 32;
  *(f16x8*)dst = o0;
  *(f16x8*)(dst + 16) = o1;
}

// ---------------------------------------------------------------------------
// Approx GEMM: s~ = -2^-7 * (zh . 256*ch) + |cb|^2  (zn omitted: per-query const)
// 128x128 tile, 4 waves (2x2), 16x16x32 f16 MFMA, K=256 in 8 chunks.
// LDS layout: row r = 64B, 16B slot s holds global cseg = s ^ ((r>>1)&3).
// Writes per-(q, ntile) top-2 partials.
// ---------------------------------------------------------------------------
__global__ __launch_bounds__(256) void vq_gemm(const char* __restrict__ At,
                                               const char* __restrict__ Bt,
                                               const float* __restrict__ cbnorm,
                                               float* __restrict__ pv1,
                                               int* __restrict__ pi1,
                                               float* __restrict__ pv2) {
  __shared__ __align__(16) char As[8192];
  __shared__ __align__(16) char Bs[8192];
  __shared__ float Bn[128];
  __shared__ float mv1[256];
  __shared__ int mi1[256];
  __shared__ float mv2[256];

  const int tid = threadIdx.x;
  const int mt = blockIdx.x & 127, nt = blockIdx.x >> 7;
  const int wave = tid >> 6, lane = tid & 63;
  const int wm = wave >> 1, wn = wave & 1;
  const int col = lane & 15, quad = lane >> 4;

  if (tid < 128) Bn[tid] = cbnorm[nt * 128 + tid];

  f32x4 acc[4][4];
#pragma unroll
  for (int i = 0; i < 4; ++i)
#pragma unroll
    for (int j = 0; j < 4; ++j) acc[i][j] = (f32x4){0.f, 0.f, 0.f, 0.f};

  int aoff[4], boff[4];
#pragma unroll
  for (int i = 0; i < 4; ++i) {
    const int m = wm * 64 + i * 16 + col;
    aoff[i] = m * 64 + ((quad ^ ((m >> 1) & 3)) << 4);
    const int n = wn * 64 + i * 16 + col;
    boff[i] = n * 64 + ((quad ^ ((n >> 1) & 3)) << 4);
  }
  const int sr = wave * 32 + (lane >> 2);
  const int ss = lane & 3;
  const char* Abase = At + (size_t)(mt * 8) * 8192;
  const char* Bbase = Bt + (size_t)(nt * 8) * 8192;

  for (int ct = 0; ct < 8; ++ct) {
    __syncthreads();
#pragma unroll
    for (int i = 0; i < 2; ++i) {
      const int r = sr + i * 16;
      const int cs = ss ^ ((r >> 1) & 3);
      async_lds16(As + wave * 2048 + i * 1024, Abase + (size_t)ct * 8192 + r * 64 + cs * 16);
      async_lds16(Bs + wave * 2048 + i * 1024, Bbase + (size_t)ct * 8192 + r * 64 + cs * 16);
    }
    __syncthreads();
    f16x8 af[4], bf[4];
#pragma unroll
    for (int i = 0; i < 4; ++i) {
      af[i] = *(const f16x8*)(As + aoff[i]);
      bf[i] = *(const f16x8*)(Bs + boff[i]);
    }
#pragma unroll
    for (int i = 0; i < 4; ++i)
#pragma unroll
      for (int j = 0; j < 4; ++j)
        acc[i][j] = __builtin_amdgcn_mfma_f32_16x16x32_f16(af[i], bf[j], acc[i][j], 0, 0, 0);
  }

  // Epilogue: C/D layout col=lane&15, row=quad*4+reg (verified m89/m91).
#pragma unroll
  for (int i = 0; i < 4; ++i) {
#pragma unroll
    for (int r = 0; r < 4; ++r) {
      float v1 = 3.4e38f, v2 = 3.4e38f;
      int i1 = 0x7fffffff;
#pragma unroll
      for (int j = 0; j < 4; ++j) {
        const int nl = wn * 64 + j * 16 + col;
        const int n = nt * 128 + nl;
        const float s = __builtin_fmaf(acc[i][j][r], -0.0078125f, Bn[nl]);
        if (s < v1) { v2 = v1; v1 = s; i1 = n; }
        else if (s < v2) v2 = s;
      }
#pragma unroll
      for (int d = 1; d < 16; d <<= 1) {
        const float ov1 = __shfl_xor(v1, d, 64);
        const int oi1 = __shfl_xor(i1, d, 64);
        const float ov2 = __shfl_xor(v2, d, 64);
        if (ov1 < v1 || (ov1 == v1 && oi1 < i1)) {
          v2 = fminf(v1, ov2); v1 = ov1; i1 = oi1;
        } else {
          v2 = fminf(v2, ov1);
        }
      }
      if (col == 0) {
        const int ql = wm * 64 + i * 16 + quad * 4 + r;
        mv1[ql * 2 + wn] = v1; mi1[ql * 2 + wn] = i1; mv2[ql * 2 + wn] = v2;
      }
    }
  }
  __syncthreads();
  if (tid < 128) {
    float v1 = mv1[tid * 2], v2 = mv2[tid * 2];
    int i1 = mi1[tid * 2];
    const float ov1 = mv1[tid * 2 + 1], ov2 = mv2[tid * 2 + 1];
    const int oi1 = mi1[tid * 2 + 1];
    if (ov1 < v1 || (ov1 == v1 && oi1 < i1)) { v2 = fminf(v1, ov2); v1 = ov1; i1 = oi1; }
    else v2 = fminf(v2, ov1);
    const int q = mt * 128 + tid;
    pv1[nt * NQ + q] = v1;
    pi1[nt * NQ + q] = i1;
    pv2[nt * NQ + q] = v2;
  }
}

// ---------------------------------------------------------------------------
// Global top-2 reduce over 64 ntile partials; flag ambiguous queries.
// ---------------------------------------------------------------------------
__global__ __launch_bounds__(128) void reduce_flag(const float* __restrict__ pv1,
                                                   const int* __restrict__ pi1,
                                                   const float* __restrict__ pv2,
                                                   int* __restrict__ idxf,
                                                   int* __restrict__ flagged,
                                                   int* __restrict__ count) {
  const int q = blockIdx.x * 128 + threadIdx.x;
  float v1 = pv1[q], v2 = pv2[q];
  int i1 = pi1[q];
  for (int nt = 1; nt < 64; ++nt) {
    const float ov1 = pv1[nt * NQ + q];
    const int oi1 = pi1[nt * NQ + q];
    const float ov2 = pv2[nt * NQ + q];
    if (ov1 < v1 || (ov1 == v1 && oi1 < i1)) { v2 = fminf(v1, ov2); v1 = ov1; i1 = oi1; }
    else v2 = fminf(v2, ov1);
  }
  idxf[q] = i1;
  if (!(v2 - v1 > MARGIN)) {
    const int p = atomicAdd(count, 1);
    flagged[p] = q;
  }
}

// ---------------------------------------------------------------------------
// Exact np-chain rescore for flagged queries. Item = (group of 32 q, slice of
// 128 codes). Thread: 1 code x 16 queries, full sequential fp32 FMA chain.
// ---------------------------------------------------------------------------
__global__ __launch_bounds__(256) void vq_exact(const float* __restrict__ z,
                                                const float* __restrict__ cb,
                                                const float* __restrict__ cbnorm,
                                                const float* __restrict__ znorm,
                                                const int* __restrict__ flagged,
                                                const int* __restrict__ count,
                                                unsigned long long* __restrict__ packed) {
  __shared__ float zT[256 * 36];  // [c][q 32] pad 36
  __shared__ int qloc[32];
  const int tid = threadIdx.x;
  const int cnt = *count;
  const int nitems = ((cnt + 31) >> 5) << 6;
  for (int w = blockIdx.x; w < nitems; w += gridDim.x) {
    const int qg = w >> 6, slice = w & 63;
    __syncthreads();
    if (tid < 32) {
      const int f = qg * 32 + tid;
      qloc[tid] = flagged[f < cnt ? f : 0];
    }
    __syncthreads();
    {
      const int qi = tid & 31, cg = tid >> 5;
      const int q = qloc[qi], bb = q >> 10, hw = q & 1023;
#pragma unroll
      for (int cc = 0; cc < 32; ++cc) {
        const int c = cg * 32 + cc;
        zT[c * 36 + qi] = z[bb * (FEAT * 1024) + c * 1024 + hw];
      }
    }
    __syncthreads();
    const int kl = tid >> 1, qh = tid & 1;
    const int k = slice * 128 + kl;
    float dot[16];
#pragma unroll
    for (int e = 0; e < 16; ++e) dot[e] = 0.f;
    const float4* row = (const float4*)(cb + (size_t)k * FEAT);
    for (int c4 = 0; c4 < 64; ++c4) {
      const float4 cv = row[c4];
#pragma unroll
      for (int e = 0; e < 4; ++e) {
        const int c = c4 * 4 + e;
        const float cc = (e == 0) ? cv.x : (e == 1) ? cv.y : (e == 2) ? cv.z : cv.w;
        const float4 z0 = *(const float4*)&zT[c * 36 + qh * 16];
        const float4 z1 = *(const float4*)&zT[c * 36 + qh * 16 + 4];
        const float4 z2 = *(const float4*)&zT[c * 36 + qh * 16 + 8];
        const float4 z3 = *(const float4*)&zT[c * 36 + qh * 16 + 12];
        dot[0] = __builtin_fmaf(z0.x, cc, dot[0]);
        dot[1] = __builtin_fmaf(z0.y, cc, dot[1]);
        dot[2] = __builtin_fmaf(z0.z, cc, dot[2]);
        dot[3] = __builtin_fmaf(z0.w, cc, dot[3]);
        dot[4] = __builtin_fmaf(z1.x, cc, dot[4]);
        dot[5] = __builtin_fmaf(z1.y, cc, dot[5]);
        dot[6] = __builtin_fmaf(z1.z, cc, dot[6]);
        dot[7] = __builtin_fmaf(z1.w, cc, dot[7]);
        dot[8] = __builtin_fmaf(z2.x, cc, dot[8]);
        dot[9] = __builtin_fmaf(z2.y, cc, dot[9]);
        dot[10] = __builtin_fmaf(z2.z, cc, dot[10]);
        dot[11] = __builtin_fmaf(z2.w, cc, dot[11]);
        dot[12] = __builtin_fmaf(z3.x, cc, dot[12]);
        dot[13] = __builtin_fmaf(z3.y, cc, dot[13]);
        dot[14] = __builtin_fmaf(z3.z, cc, dot[14]);
        dot[15] = __builtin_fmaf(z3.w, cc, dot[15]);
      }
    }
    const float cn = cbnorm[k];
    unsigned long long key[16];
#pragma unroll
    for (int e = 0; e < 16; ++e) {
      const int q = qloc[qh * 16 + e];
      const float s = __fadd_rn(__fadd_rn(__fmul_rn(-2.0f, dot[e]), znorm[q]), cn);
      unsigned u = __float_as_uint(s);
      u = (u & 0x80000000u) ? ~u : (u | 0x80000000u);
      key[e] = ((unsigned long long)u << 32) | (unsigned)k;
    }
#pragma unroll
    for (int d = 2; d <= 32; d <<= 1) {
#pragma unroll
      for (int e = 0; e < 16; ++e) {
        const unsigned long long o = __shfl_xor(key[e], d, 64);
        if (o < key[e]) key[e] = o;
      }
    }
    if (((tid >> 1) & 31) == 0) {
#pragma unroll
      for (int e = 0; e < 16; ++e) atomicMin(&packed[qloc[qh * 16 + e]], key[e]);
    }
  }
}

// ---------------------------------------------------------------------------
// Gather: zq[b][c][hw] = cb[idx]; idx (exact overrides approx) as float.
// ---------------------------------------------------------------------------
__global__ __launch_bounds__(256) void vq_gather(const float* __restrict__ cb,
                                                 const unsigned long long* __restrict__ packed,
                                                 const int* __restrict__ idxf,
                                                 float* __restrict__ out) {
  const int q0 = blockIdx.x * 64;
  const int nl = threadIdx.x & 63;
  const int cg = threadIdx.x >> 6;
  const int q = q0 + nl;
  const unsigned long long pk = packed[q];
  const int kq = (pk != ~0ULL) ? (int)(unsigned)pk : idxf[q];
  const int b = q >> 10, hw = q & 1023;
  const float4* cb4 = (const float4*)cb;
#pragma unroll
  for (int t = 0; t < 16; ++t) {
    const int cc = cg + t * 4;
    const float4 v = cb4[kq * 64 + cc];
    const int base = b * (FEAT * 1024) + (cc * 4) * 1024 + hw;
    out[base] = v.x;
    out[base + 1024] = v.y;
    out[base + 2048] = v.z;
    out[base + 3072] = v.w;
  }
  if (threadIdx.x < 64) {
    const int qq = q0 + threadIdx.x;
    const unsigned long long p2 = packed[qq];
    const int k2 = (p2 != ~0ULL) ? (int)(unsigned)p2 : idxf[qq];
    out[ZQ_ELEMS + qq] = (float)k2;
  }
}

extern "C" void kernel_launch(void* const* d_in, const int* in_sizes, int n_in,
                              void* d_out, int out_size, void* d_ws, size_t ws_size,
                              hipStream_t stream) {
  const float* z = (const float*)d_in[0];
  const float* cb = (const float*)d_in[1];
  char* w = (char*)d_ws;
  // ws layout (24.4 MB total)
  char* At = w;                                   // 8 MB fp16 tiled A
  char* Bt = w + 8388608;                         // 4 MB fp16 tiled B (x256)
  float* pv1 = (float*)(w + 12582912);            // 4 MB
  int* pi1 = (int*)(w + 16777216);                // 4 MB
  float* pv2 = (float*)(w + 20971520);            // 4 MB
  float* cbnorm = (float*)(w + 25165824);         // 32 KB
  float* znorm = (float*)(w + 25198592);          // 64 KB
  int* idxf = (int*)(w + 25264128);               // 64 KB
  int* flagged = (int*)(w + 25329664);            // 64 KB
  int* count = (int*)(w + 25395200);              // 256 B
  unsigned long long* packed = (unsigned long long*)(w + 25395456);  // 128 KB

  hipMemsetAsync(count, 0, 256, stream);
  hipMemsetAsync(packed, 0xFF, NQ * sizeof(unsigned long long), stream);
  norms_kernel<<<(CODES + NQ) / 16, 256, 0, stream>>>(cb, z, cbnorm, znorm);
  convA<<<1024, 256, 0, stream>>>(z, At);
  convB<<<512, 256, 0, stream>>>(cb, Bt);
  vq_gemm<<<8192, 256, 0, stream>>>(At, Bt, cbnorm, pv1, pi1, pv2);
  reduce_flag<<<128, 128, 0, stream>>>(pv1, pi1, pv2, idxf, flagged, count);
  vq_exact<<<4096, 256, 0, stream>>>(z, cb, cbnorm, znorm, flagged, count, packed);
  vq_gather<<<256, 256, 0, stream>>>(cb, packed, idxf, (float*)d_out);
}

// Round 3
// 529.273 us; speedup vs baseline: 1.7655x; 1.0667x over previous
//
#include <hip/hip_runtime.h>
#include <stdint.h>

#define FEAT 256
#define CODES 8192
#define NQ 16384                 // 16*32*32
#define ZQ_ELEMS (NQ * FEAT)
#define MARGIN 2.5e-3f
#define KSPLIT 4

typedef _Float16 f16x8 __attribute__((ext_vector_type(8)));
typedef float f32x4 __attribute__((ext_vector_type(4)));

// global -> LDS direct DMA, 16B per lane. LDS dst = uniform base + lane*16.
__device__ __forceinline__ void async_lds16(void* lds, const void* g) {
  __builtin_amdgcn_global_load_lds(
      (const __attribute__((address_space(1))) void*)(uintptr_t)(g),
      (__attribute__((address_space(3))) void*)(uint32_t)(uintptr_t)(lds),
      16, 0, 0);
}

// ---------------------------------------------------------------------------
// numpy pairwise sum-of-squares replication (passed R1/R2 with absmax 0).
// ---------------------------------------------------------------------------
template <int STRIDE>
__device__ __forceinline__ float pairwise256_sq(const float* __restrict__ base, int lane16) {
  const int h = lane16 >> 3, j = lane16 & 7;
  const float* p = base + (h * 128 + j) * STRIDE;
  float x = p[0];
  float r = __fmul_rn(x, x);
#pragma unroll
  for (int i = 1; i < 16; ++i) {
    float y = p[i * 8 * STRIDE];
    r = __fadd_rn(r, __fmul_rn(y, y));
  }
  r = __fadd_rn(r, __shfl_xor(r, 1, 64));
  r = __fadd_rn(r, __shfl_xor(r, 2, 64));
  r = __fadd_rn(r, __shfl_xor(r, 4, 64));
  float other = __shfl_xor(r, 8, 64);
  float lo = (h == 0) ? r : other;
  float hi = (h == 0) ? other : r;
  return __fadd_rn(lo, hi);
}

__global__ __launch_bounds__(256) void norms_kernel(const float* __restrict__ cb,
                                                    const float* __restrict__ z,
                                                    float* __restrict__ cbnorm,
                                                    float* __restrict__ znorm) {
  const int g = (blockIdx.x * 256 + threadIdx.x) >> 4;
  const int lane16 = threadIdx.x & 15;
  if (g < CODES) {
    float v = pairwise256_sq<1>(cb + g * FEAT, lane16);
    if (lane16 == 0) cbnorm[g] = v;
  } else {
    const int q = g - CODES;
    const int b = q >> 10, hw = q & 1023;
    float v = pairwise256_sq<1024>(z + b * (FEAT * 1024) + hw, lane16);
    if (lane16 == 0) znorm[q] = v;
  }
}

// ---------------------------------------------------------------------------
// convA: z fp32 -> Ah (fp16 high) + Al (fp16 residual) tiles [mt][ct][r128][c32]
// ---------------------------------------------------------------------------
__global__ __launch_bounds__(256) void convA(const float* __restrict__ z,
                                             char* __restrict__ AtH, char* __restrict__ AtL) {
  __shared__ _Float16 Th[128 * 40];
  __shared__ _Float16 Tl[128 * 40];
  const int t = threadIdx.x;
  const int mt = blockIdx.x >> 3, ct = blockIdx.x & 7;
  const int q0 = mt * 128, bb = q0 >> 10, hw0 = q0 & 1023;
  const int c0 = ct * 32;
#pragma unroll
  for (int it = 0; it < 16; ++it) {
    const int cc = it * 2 + (t >> 7);
    const int qi = t & 127;
    float v = z[bb * (FEAT * 1024) + (c0 + cc) * 1024 + hw0 + qi];
    _Float16 hh = (_Float16)v;
    Th[qi * 40 + cc] = hh;
    Tl[qi * 40 + cc] = (_Float16)(v - (float)hh);
  }
  __syncthreads();
  const int r = t >> 1, h = t & 1;
  {
    float4 a = *(const float4*)&Th[r * 40 + h * 16];
    float4 b = *(const float4*)&Th[r * 40 + h * 16 + 8];
    char* dst = AtH + (size_t)(mt * 8 + ct) * 8192 + t * 32;
    *(float4*)dst = a;
    *(float4*)(dst + 16) = b;
  }
  {
    float4 a = *(const float4*)&Tl[r * 40 + h * 16];
    float4 b = *(const float4*)&Tl[r * 40 + h * 16 + 8];
    char* dst = AtL + (size_t)(mt * 8 + ct) * 8192 + t * 32;
    *(float4*)dst = a;
    *(float4*)(dst + 16) = b;
  }
}

// ---------------------------------------------------------------------------
// convB: cb fp32 -> fp16 tiles [nt][ct][n128][c32], scaled by 256
// ---------------------------------------------------------------------------
__global__ __launch_bounds__(256) void convB(const float* __restrict__ cb, char* __restrict__ Bt) {
  const int t = threadIdx.x;
  const int nt = blockIdx.x >> 3, ct = blockIdx.x & 7;
  const int n = t >> 1, h = t & 1;
  const float* src = cb + (size_t)(nt * 128 + n) * FEAT + ct * 32 + h * 16;
  f16x8 o0, o1;
#pragma unroll
  for (int e = 0; e < 8; ++e) o0[e] = (_Float16)(src[e] * 256.0f);
#pragma unroll
  for (int e = 0; e < 8; ++e) o1[e] = (_Float16)(src[8 + e] * 256.0f);
  char* dst = Bt + (size_t)(nt * 8 + ct) * 8192 + t * 32;
  *(f16x8*)dst = o0;
  *(f16x8*)(dst + 16) = o1;
}

// ---------------------------------------------------------------------------
// Split-precision GEMM + running top-2. Block: 128 q x 2048 codes (16 ntiles),
// KSPLIT=4 -> 512 blocks. acc = zh.ch + zl.ch (one fp32 accumulator).
// Per-thread running top-2 per query-row in registers; one epilogue per block.
// ---------------------------------------------------------------------------
__global__ __launch_bounds__(256, 2) void vq_gemm(const char* __restrict__ AtH,
                                                  const char* __restrict__ AtL,
                                                  const char* __restrict__ Bt,
                                                  const float* __restrict__ cbnorm,
                                                  float* __restrict__ pv1,
                                                  int* __restrict__ pi1,
                                                  float* __restrict__ pv2) {
  __shared__ __align__(16) char AsH[8192];
  __shared__ __align__(16) char AsL[8192];
  __shared__ __align__(16) char Bs[8192];
  __shared__ float mv1[256];
  __shared__ int mi1[256];
  __shared__ float mv2[256];

  const int tid = threadIdx.x;
  const int mt = blockIdx.x >> 2, ks = blockIdx.x & 3;
  const int wave = tid >> 6, lane = tid & 63;
  const int wm = wave >> 1, wn = wave & 1;
  const int col = lane & 15, quad = lane >> 4;

  int aoff[4], boff[4];
#pragma unroll
  for (int i = 0; i < 4; ++i) {
    const int m = wm * 64 + i * 16 + col;
    aoff[i] = m * 64 + ((quad ^ ((m >> 1) & 3)) << 4);
    const int n = wn * 64 + i * 16 + col;
    boff[i] = n * 64 + ((quad ^ ((n >> 1) & 3)) << 4);
  }
  const int sr = wave * 32 + (lane >> 2);
  const int ss = lane & 3;
  const char* AbaseH = AtH + (size_t)(mt * 8) * 8192;
  const char* AbaseL = AtL + (size_t)(mt * 8) * 8192;

  float tv1[16], tv2[16];
  int ti1[16];
#pragma unroll
  for (int r = 0; r < 16; ++r) { tv1[r] = 3.4e38f; tv2[r] = 3.4e38f; ti1[r] = 0x7fffffff; }

  for (int nt = 0; nt < 16; ++nt) {
    const int ntile = ks * 16 + nt;
    const char* Bbase = Bt + (size_t)(ntile * 8) * 8192;
    f32x4 acc[4][4];
#pragma unroll
    for (int i = 0; i < 4; ++i)
#pragma unroll
      for (int j = 0; j < 4; ++j) acc[i][j] = (f32x4){0.f, 0.f, 0.f, 0.f};

    for (int ct = 0; ct < 8; ++ct) {
      __syncthreads();
#pragma unroll
      for (int i = 0; i < 2; ++i) {
        const int r = sr + i * 16;
        const int cs = ss ^ ((r >> 1) & 3);
        const size_t go = (size_t)ct * 8192 + r * 64 + cs * 16;
        async_lds16(AsH + wave * 2048 + i * 1024, AbaseH + go);
        async_lds16(AsL + wave * 2048 + i * 1024, AbaseL + go);
        async_lds16(Bs + wave * 2048 + i * 1024, Bbase + go);
      }
      __syncthreads();
      f16x8 af[4], alf[4], bf[4];
#pragma unroll
      for (int i = 0; i < 4; ++i) {
        af[i] = *(const f16x8*)(AsH + aoff[i]);
        alf[i] = *(const f16x8*)(AsL + aoff[i]);
        bf[i] = *(const f16x8*)(Bs + boff[i]);
      }
#pragma unroll
      for (int i = 0; i < 4; ++i)
#pragma unroll
        for (int j = 0; j < 4; ++j) {
          acc[i][j] = __builtin_amdgcn_mfma_f32_16x16x32_f16(af[i], bf[j], acc[i][j], 0, 0, 0);
          acc[i][j] = __builtin_amdgcn_mfma_f32_16x16x32_f16(alf[i], bf[j], acc[i][j], 0, 0, 0);
        }
    }
    // per-nt scoring into running top-2 (k ascending: j asc within thread, nt asc)
    const int k0 = ntile * 128;
#pragma unroll
    for (int j = 0; j < 4; ++j) {
      const int k = k0 + wn * 64 + j * 16 + col;
      const float cn = cbnorm[k];
#pragma unroll
      for (int i = 0; i < 4; ++i)
#pragma unroll
        for (int r = 0; r < 4; ++r) {
          const int row = i * 4 + r;
          const float s = __builtin_fmaf(acc[i][j][r], -0.0078125f, cn);
          if (s < tv1[row]) { tv2[row] = tv1[row]; tv1[row] = s; ti1[row] = k; }
          else if (s < tv2[row]) tv2[row] = s;
        }
    }
  }

  // Epilogue once per block: cross-col reduce, merge wn halves, store partials.
#pragma unroll
  for (int row = 0; row < 16; ++row) {
    float v1 = tv1[row], v2 = tv2[row];
    int i1 = ti1[row];
#pragma unroll
    for (int d = 1; d < 16; d <<= 1) {
      const float ov1 = __shfl_xor(v1, d, 64);
      const int oi1 = __shfl_xor(i1, d, 64);
      const float ov2 = __shfl_xor(v2, d, 64);
      if (ov1 < v1 || (ov1 == v1 && oi1 < i1)) { v2 = fminf(v1, ov2); v1 = ov1; i1 = oi1; }
      else v2 = fminf(v2, ov1);
    }
    if (col == 0) {
      const int ql = wm * 64 + (row >> 2) * 16 + quad * 4 + (row & 3);
      mv1[ql * 2 + wn] = v1; mi1[ql * 2 + wn] = i1; mv2[ql * 2 + wn] = v2;
    }
  }
  __syncthreads();
  if (tid < 128) {
    float v1 = mv1[tid * 2], v2 = mv2[tid * 2];
    int i1 = mi1[tid * 2];
    const float ov1 = mv1[tid * 2 + 1], ov2 = mv2[tid * 2 + 1];
    const int oi1 = mi1[tid * 2 + 1];
    if (ov1 < v1 || (ov1 == v1 && oi1 < i1)) { v2 = fminf(v1, ov2); v1 = ov1; i1 = oi1; }
    else v2 = fminf(v2, ov1);
    const int q = mt * 128 + tid;
    pv1[ks * NQ + q] = v1;
    pi1[ks * NQ + q] = i1;
    pv2[ks * NQ + q] = v2;
  }
}

// ---------------------------------------------------------------------------
// Global top-2 reduce over KSPLIT partials; flag ambiguous queries.
// ---------------------------------------------------------------------------
__global__ __launch_bounds__(128) void reduce_flag(const float* __restrict__ pv1,
                                                   const int* __restrict__ pi1,
                                                   const float* __restrict__ pv2,
                                                   int* __restrict__ idxf,
                                                   int* __restrict__ flagged,
                                                   int* __restrict__ count) {
  const int q = blockIdx.x * 128 + threadIdx.x;
  float v1 = pv1[q], v2 = pv2[q];
  int i1 = pi1[q];
#pragma unroll
  for (int ks = 1; ks < KSPLIT; ++ks) {
    const float ov1 = pv1[ks * NQ + q];
    const int oi1 = pi1[ks * NQ + q];
    const float ov2 = pv2[ks * NQ + q];
    if (ov1 < v1 || (ov1 == v1 && oi1 < i1)) { v2 = fminf(v1, ov2); v1 = ov1; i1 = oi1; }
    else v2 = fminf(v2, ov1);
  }
  idxf[q] = i1;
  if (!(v2 - v1 > MARGIN)) {
    const int p = atomicAdd(count, 1);
    flagged[p] = q;
  }
}

// ---------------------------------------------------------------------------
// Exact np-chain rescore for flagged queries (unchanged from R2 — verified).
// ---------------------------------------------------------------------------
__global__ __launch_bounds__(256) void vq_exact(const float* __restrict__ z,
                                                const float* __restrict__ cb,
                                                const float* __restrict__ cbnorm,
                                                const float* __restrict__ znorm,
                                                const int* __restrict__ flagged,
                                                const int* __restrict__ count,
                                                unsigned long long* __restrict__ packed) {
  __shared__ float zT[256 * 36];
  __shared__ int qloc[32];
  const int tid = threadIdx.x;
  const int cnt = *count;
  const int nitems = ((cnt + 31) >> 5) << 6;
  for (int w = blockIdx.x; w < nitems; w += gridDim.x) {
    const int qg = w >> 6, slice = w & 63;
    __syncthreads();
    if (tid < 32) {
      const int f = qg * 32 + tid;
      qloc[tid] = flagged[f < cnt ? f : 0];
    }
    __syncthreads();
    {
      const int qi = tid & 31, cg = tid >> 5;
      const int q = qloc[qi], bb = q >> 10, hw = q & 1023;
#pragma unroll
      for (int cc = 0; cc < 32; ++cc) {
        const int c = cg * 32 + cc;
        zT[c * 36 + qi] = z[bb * (FEAT * 1024) + c * 1024 + hw];
      }
    }
    __syncthreads();
    const int kl = tid >> 1, qh = tid & 1;
    const int k = slice * 128 + kl;
    float dot[16];
#pragma unroll
    for (int e = 0; e < 16; ++e) dot[e] = 0.f;
    const float4* row = (const float4*)(cb + (size_t)k * FEAT);
    for (int c4 = 0; c4 < 64; ++c4) {
      const float4 cv = row[c4];
#pragma unroll
      for (int e = 0; e < 4; ++e) {
        const int c = c4 * 4 + e;
        const float cc = (e == 0) ? cv.x : (e == 1) ? cv.y : (e == 2) ? cv.z : cv.w;
        const float4 z0 = *(const float4*)&zT[c * 36 + qh * 16];
        const float4 z1 = *(const float4*)&zT[c * 36 + qh * 16 + 4];
        const float4 z2 = *(const float4*)&zT[c * 36 + qh * 16 + 8];
        const float4 z3 = *(const float4*)&zT[c * 36 + qh * 16 + 12];
        dot[0] = __builtin_fmaf(z0.x, cc, dot[0]);
        dot[1] = __builtin_fmaf(z0.y, cc, dot[1]);
        dot[2] = __builtin_fmaf(z0.z, cc, dot[2]);
        dot[3] = __builtin_fmaf(z0.w, cc, dot[3]);
        dot[4] = __builtin_fmaf(z1.x, cc, dot[4]);
        dot[5] = __builtin_fmaf(z1.y, cc, dot[5]);
        dot[6] = __builtin_fmaf(z1.z, cc, dot[6]);
        dot[7] = __builtin_fmaf(z1.w, cc, dot[7]);
        dot[8] = __builtin_fmaf(z2.x, cc, dot[8]);
        dot[9] = __builtin_fmaf(z2.y, cc, dot[9]);
        dot[10] = __builtin_fmaf(z2.z, cc, dot[10]);
        dot[11] = __builtin_fmaf(z2.w, cc, dot[11]);
        dot[12] = __builtin_fmaf(z3.x, cc, dot[12]);
        dot[13] = __builtin_fmaf(z3.y, cc, dot[13]);
        dot[14] = __builtin_fmaf(z3.z, cc, dot[14]);
        dot[15] = __builtin_fmaf(z3.w, cc, dot[15]);
      }
    }
    const float cn = cbnorm[k];
    unsigned long long key[16];
#pragma unroll
    for (int e = 0; e < 16; ++e) {
      const int q = qloc[qh * 16 + e];
      const float s = __fadd_rn(__fadd_rn(__fmul_rn(-2.0f, dot[e]), znorm[q]), cn);
      unsigned u = __float_as_uint(s);
      u = (u & 0x80000000u) ? ~u : (u | 0x80000000u);
      key[e] = ((unsigned long long)u << 32) | (unsigned)k;
    }
#pragma unroll
    for (int d = 2; d <= 32; d <<= 1) {
#pragma unroll
      for (int e = 0; e < 16; ++e) {
        const unsigned long long o = __shfl_xor(key[e], d, 64);
        if (o < key[e]) key[e] = o;
      }
    }
    if (((tid >> 1) & 31) == 0) {
#pragma unroll
      for (int e = 0; e < 16; ++e) atomicMin(&packed[qloc[qh * 16 + e]], key[e]);
    }
  }
}

// ---------------------------------------------------------------------------
// Gather: zq[b][c][hw] = cb[idx]; idx (exact overrides approx) as float.
// ---------------------------------------------------------------------------
__global__ __launch_bounds__(256) void vq_gather(const float* __restrict__ cb,
                                                 const unsigned long long* __restrict__ packed,
                                                 const int* __restrict__ idxf,
                                                 float* __restrict__ out) {
  const int q0 = blockIdx.x * 64;
  const int nl = threadIdx.x & 63;
  const int cg = threadIdx.x >> 6;
  const int q = q0 + nl;
  const unsigned long long pk = packed[q];
  const int kq = (pk != ~0ULL) ? (int)(unsigned)pk : idxf[q];
  const int b = q >> 10, hw = q & 1023;
  const float4* cb4 = (const float4*)cb;
#pragma unroll
  for (int t = 0; t < 16; ++t) {
    const int cc = cg + t * 4;
    const float4 v = cb4[kq * 64 + cc];
    const int base = b * (FEAT * 1024) + (cc * 4) * 1024 + hw;
    out[base] = v.x;
    out[base + 1024] = v.y;
    out[base + 2048] = v.z;
    out[base + 3072] = v.w;
  }
  if (threadIdx.x < 64) {
    const int qq = q0 + threadIdx.x;
    const unsigned long long p2 = packed[qq];
    const int k2 = (p2 != ~0ULL) ? (int)(unsigned)p2 : idxf[qq];
    out[ZQ_ELEMS + qq] = (float)k2;
  }
}

extern "C" void kernel_launch(void* const* d_in, const int* in_sizes, int n_in,
                              void* d_out, int out_size, void* d_ws, size_t ws_size,
                              hipStream_t stream) {
  const float* z = (const float*)d_in[0];
  const float* cb = (const float*)d_in[1];
  char* w = (char*)d_ws;
  // ws layout (~21.1 MB)
  char* AtH = w;                                   // 8 MB
  char* AtL = w + 8388608;                         // 8 MB
  char* Bt = w + 16777216;                         // 4 MB
  float* pv1 = (float*)(w + 20971520);             // 256 KB
  int* pi1 = (int*)(w + 21233664);                 // 256 KB
  float* pv2 = (float*)(w + 21495808);             // 256 KB
  float* cbnorm = (float*)(w + 21757952);          // 32 KB
  float* znorm = (float*)(w + 21790720);           // 64 KB
  int* idxf = (int*)(w + 21856256);                // 64 KB
  int* flagged = (int*)(w + 21921792);             // 64 KB
  int* count = (int*)(w + 21987328);               // 256 B
  unsigned long long* packed = (unsigned long long*)(w + 21987584);  // 128 KB

  hipMemsetAsync(count, 0, 256, stream);
  hipMemsetAsync(packed, 0xFF, NQ * sizeof(unsigned long long), stream);
  norms_kernel<<<(CODES + NQ) / 16, 256, 0, stream>>>(cb, z, cbnorm, znorm);
  convA<<<1024, 256, 0, stream>>>(z, AtH, AtL);
  convB<<<512, 256, 0, stream>>>(cb, Bt);
  vq_gemm<<<(NQ / 128) * KSPLIT, 256, 0, stream>>>(AtH, AtL, Bt, cbnorm, pv1, pi1, pv2);
  reduce_flag<<<NQ / 128, 128, 0, stream>>>(pv1, pi1, pv2, idxf, flagged, count);
  vq_exact<<<4096, 256, 0, stream>>>(z, cb, cbnorm, znorm, flagged, count, packed);
  vq_gather<<<NQ / 64, 256, 0, stream>>>(cb, packed, idxf, (float*)d_out);
}

// Round 4
// 466.717 us; speedup vs baseline: 2.0022x; 1.1340x over previous
//
#include <hip/hip_runtime.h>
#include <stdint.h>

#define FEAT 256
#define CODES 8192
#define NQ 16384                 // 16*32*32
#define ZQ_ELEMS (NQ * FEAT)
#define MARGIN 2e-3f             // = 2e; e_worst ~ 9.3e-4 (fp16 A + fp16 B rounding)
#define NSLICE 8                 // one 1024-code slice per XCD
#define CAP_PAIRS (1 << 19)      // 512K pairs (expected ~4K)

typedef _Float16 f16x8 __attribute__((ext_vector_type(8)));
typedef float f32x4 __attribute__((ext_vector_type(4)));

__device__ __forceinline__ void async_lds16(void* lds, const void* g) {
  __builtin_amdgcn_global_load_lds(
      (const __attribute__((address_space(1))) void*)(uintptr_t)(g),
      (__attribute__((address_space(3))) void*)(uint32_t)(uintptr_t)(lds),
      16, 0, 0);
}

__device__ __forceinline__ bool lexless(float v, int i, float w, int j) {
  return v < w || (v == w && i < j);
}

// merge sorted triple (ov*) into sorted triple (v1,i1,v2,i2,v3); v3 value-only
__device__ __forceinline__ void merge3(float& v1, int& i1, float& v2, int& i2, float& v3,
                                       float ov1, int oi1, float ov2, int oi2, float ov3) {
  if (lexless(ov1, oi1, v1, i1)) {
    if (lexless(v1, i1, ov2, oi2)) { v3 = fminf(v2, ov2); v2 = v1; i2 = i1; }
    else                           { v3 = fminf(v1, ov3); v2 = ov2; i2 = oi2; }
    v1 = ov1; i1 = oi1;
  } else {
    if (lexless(ov1, oi1, v2, i2)) { v3 = fminf(v2, ov2); v2 = ov1; i2 = oi1; }
    else                           { v3 = fminf(v3, ov1); }
  }
}

// ---------------------------------------------------------------------------
// numpy pairwise sum-of-squares replication (verified R1-R3, absmax 0).
// ---------------------------------------------------------------------------
template <int STRIDE>
__device__ __forceinline__ float pairwise256_sq(const float* __restrict__ base, int lane16) {
  const int h = lane16 >> 3, j = lane16 & 7;
  const float* p = base + (h * 128 + j) * STRIDE;
  float x = p[0];
  float r = __fmul_rn(x, x);
#pragma unroll
  for (int i = 1; i < 16; ++i) {
    float y = p[i * 8 * STRIDE];
    r = __fadd_rn(r, __fmul_rn(y, y));
  }
  r = __fadd_rn(r, __shfl_xor(r, 1, 64));
  r = __fadd_rn(r, __shfl_xor(r, 2, 64));
  r = __fadd_rn(r, __shfl_xor(r, 4, 64));
  float other = __shfl_xor(r, 8, 64);
  float lo = (h == 0) ? r : other;
  float hi = (h == 0) ? other : r;
  return __fadd_rn(lo, hi);
}

__global__ __launch_bounds__(256) void norms_kernel(const float* __restrict__ cb,
                                                    const float* __restrict__ z,
                                                    float* __restrict__ cbnorm,
                                                    float* __restrict__ znorm) {
  const int g = (blockIdx.x * 256 + threadIdx.x) >> 4;
  const int lane16 = threadIdx.x & 15;
  if (g < CODES) {
    float v = pairwise256_sq<1>(cb + g * FEAT, lane16);
    if (lane16 == 0) cbnorm[g] = v;
  } else {
    const int q = g - CODES;
    const int b = q >> 10, hw = q & 1023;
    float v = pairwise256_sq<1024>(z + b * (FEAT * 1024) + hw, lane16);
    if (lane16 == 0) znorm[q] = v;
  }
}

// ---------------------------------------------------------------------------
// convA: z fp32 -> fp16 tiles [mt][ct][r128][c32]
// ---------------------------------------------------------------------------
__global__ __launch_bounds__(256) void convA(const float* __restrict__ z, char* __restrict__ At) {
  __shared__ _Float16 T[128 * 40];
  const int t = threadIdx.x;
  const int mt = blockIdx.x >> 3, ct = blockIdx.x & 7;
  const int q0 = mt * 128, bb = q0 >> 10, hw0 = q0 & 1023;
  const int c0 = ct * 32;
#pragma unroll
  for (int it = 0; it < 16; ++it) {
    const int cc = it * 2 + (t >> 7);
    const int qi = t & 127;
    float v = z[bb * (FEAT * 1024) + (c0 + cc) * 1024 + hw0 + qi];
    T[qi * 40 + cc] = (_Float16)v;
  }
  __syncthreads();
  const int r = t >> 1, h = t & 1;
  float4 a = *(const float4*)&T[r * 40 + h * 16];
  float4 b = *(const float4*)&T[r * 40 + h * 16 + 8];
  char* dst = At + (size_t)(mt * 8 + ct) * 8192 + t * 32;
  *(float4*)dst = a;
  *(float4*)(dst + 16) = b;
}

// ---------------------------------------------------------------------------
// convB: cb fp32 -> fp16 tiles [nt][ct][n128][c32], scaled by 256
// ---------------------------------------------------------------------------
__global__ __launch_bounds__(256) void convB(const float* __restrict__ cb, char* __restrict__ Bt) {
  const int t = threadIdx.x;
  const int nt = blockIdx.x >> 3, ct = blockIdx.x & 7;
  const int n = t >> 1, h = t & 1;
  const float* src = cb + (size_t)(nt * 128 + n) * FEAT + ct * 32 + h * 16;
  f16x8 o0, o1;
#pragma unroll
  for (int e = 0; e < 8; ++e) o0[e] = (_Float16)(src[e] * 256.0f);
#pragma unroll
  for (int e = 0; e < 8; ++e) o1[e] = (_Float16)(src[8 + e] * 256.0f);
  char* dst = Bt + (size_t)(nt * 8 + ct) * 8192 + t * 32;
  *(f16x8*)dst = o0;
  *(f16x8*)(dst + 16) = o1;
}

// ---------------------------------------------------------------------------
// fp16 GEMM + per-slice top-3. Block: 128 q x 1024 codes (one XCD-pinned
// slice; slice = blockIdx & 7 so each XCD's L2 holds one 512 KB B-slice).
// Tracks per-row top-3 values + top-2 indices for the candidate-window test.
// ---------------------------------------------------------------------------
__global__ __launch_bounds__(256, 2) void vq_gemm(const char* __restrict__ At,
                                                  const char* __restrict__ Bt,
                                                  const float* __restrict__ cbnorm,
                                                  float4* __restrict__ pvi,
                                                  float* __restrict__ pv3) {
  __shared__ __align__(16) char As[8192];
  __shared__ __align__(16) char Bs[8192];
  __shared__ float4 mvi[256];
  __shared__ float mv3[256];

  const int tid = threadIdx.x;
  const int slice = blockIdx.x & 7, mt = blockIdx.x >> 3;
  const int wave = tid >> 6, lane = tid & 63;
  const int wm = wave >> 1, wn = wave & 1;
  const int col = lane & 15, quad = lane >> 4;

  int aoff[4], boff[4];
#pragma unroll
  for (int i = 0; i < 4; ++i) {
    const int m = wm * 64 + i * 16 + col;
    aoff[i] = m * 64 + ((quad ^ ((m >> 1) & 3)) << 4);
    const int n = wn * 64 + i * 16 + col;
    boff[i] = n * 64 + ((quad ^ ((n >> 1) & 3)) << 4);
  }
  const int sr = wave * 32 + (lane >> 2);
  const int ss = lane & 3;
  const char* Abase = At + (size_t)(mt * 8) * 8192;

  float tv1[16], tv2[16], tv3[16];
  int ti1[16], ti2[16];
#pragma unroll
  for (int r = 0; r < 16; ++r) {
    tv1[r] = 3.4e38f; tv2[r] = 3.4e38f; tv3[r] = 3.4e38f;
    ti1[r] = 0x7fffffff; ti2[r] = 0x7fffffff;
  }

  for (int nt = 0; nt < 8; ++nt) {
    const int ntile = slice * 8 + nt;
    const char* Bbase = Bt + (size_t)(ntile * 8) * 8192;
    f32x4 acc[4][4];
#pragma unroll
    for (int i = 0; i < 4; ++i)
#pragma unroll
      for (int j = 0; j < 4; ++j) acc[i][j] = (f32x4){0.f, 0.f, 0.f, 0.f};

    for (int ct = 0; ct < 8; ++ct) {
      __syncthreads();
#pragma unroll
      for (int i = 0; i < 2; ++i) {
        const int r = sr + i * 16;
        const int cs = ss ^ ((r >> 1) & 3);
        const size_t go = (size_t)ct * 8192 + r * 64 + cs * 16;
        async_lds16(As + wave * 2048 + i * 1024, Abase + go);
        async_lds16(Bs + wave * 2048 + i * 1024, Bbase + go);
      }
      __syncthreads();
      f16x8 af[4], bf[4];
#pragma unroll
      for (int i = 0; i < 4; ++i) {
        af[i] = *(const f16x8*)(As + aoff[i]);
        bf[i] = *(const f16x8*)(Bs + boff[i]);
      }
#pragma unroll
      for (int i = 0; i < 4; ++i)
#pragma unroll
        for (int j = 0; j < 4; ++j)
          acc[i][j] = __builtin_amdgcn_mfma_f32_16x16x32_f16(af[i], bf[j], acc[i][j], 0, 0, 0);
    }
    // scoring: k ascending within thread (j asc, nt asc) -> strict < keeps first
    const int k0 = ntile * 128;
#pragma unroll
    for (int j = 0; j < 4; ++j) {
      const int k = k0 + wn * 64 + j * 16 + col;
      const float cn = cbnorm[k];
#pragma unroll
      for (int i = 0; i < 4; ++i)
#pragma unroll
        for (int r = 0; r < 4; ++r) {
          const int row = i * 4 + r;
          const float s = __builtin_fmaf(acc[i][j][r], -0.0078125f, cn);
          if (s < tv1[row]) {
            tv3[row] = tv2[row]; tv2[row] = tv1[row]; ti2[row] = ti1[row];
            tv1[row] = s; ti1[row] = k;
          } else if (s < tv2[row]) {
            tv3[row] = tv2[row]; tv2[row] = s; ti2[row] = k;
          } else if (s < tv3[row]) {
            tv3[row] = s;
          }
        }
    }
  }

  // epilogue: cross-col top-3 merge, then wn merge, store per-slice partials
#pragma unroll
  for (int row = 0; row < 16; ++row) {
    float v1 = tv1[row], v2 = tv2[row], v3 = tv3[row];
    int i1 = ti1[row], i2 = ti2[row];
#pragma unroll
    for (int d = 1; d < 16; d <<= 1) {
      const float ov1 = __shfl_xor(v1, d, 64);
      const int oi1 = __shfl_xor(i1, d, 64);
      const float ov2 = __shfl_xor(v2, d, 64);
      const int oi2 = __shfl_xor(i2, d, 64);
      const float ov3 = __shfl_xor(v3, d, 64);
      merge3(v1, i1, v2, i2, v3, ov1, oi1, ov2, oi2, ov3);
    }
    if (col == 0) {
      const int ql = wm * 64 + (row >> 2) * 16 + quad * 4 + (row & 3);
      mvi[ql * 2 + wn] = (float4){v1, __int_as_float(i1), v2, __int_as_float(i2)};
      mv3[ql * 2 + wn] = v3;
    }
  }
  __syncthreads();
  if (tid < 128) {
    float4 a = mvi[tid * 2];
    float4 b = mvi[tid * 2 + 1];
    float v1 = a.x, v2 = a.z, v3 = mv3[tid * 2];
    int i1 = __float_as_int(a.y), i2 = __float_as_int(a.w);
    merge3(v1, i1, v2, i2, v3, b.x, __float_as_int(b.y), b.z, __float_as_int(b.w),
           mv3[tid * 2 + 1]);
    const int q = mt * 128 + tid;
    pvi[slice * NQ + q] = (float4){v1, __int_as_float(i1), v2, __int_as_float(i2)};
    pv3[slice * NQ + q] = v3;
  }
}

// ---------------------------------------------------------------------------
// Reduce 8 slice-partials; emit candidate (q,k) pairs for ambiguous queries.
// Rigor: exact-best k* satisfies s~(k*) <= gv1 + 2e = thr, so the push set
// {all codes with s~ <= thr} covers it. Slice contribution: i1,i2 if in
// window; if slice v3 <= thr, rank-3+ unbounded -> push whole slice (rare).
// ---------------------------------------------------------------------------
__global__ __launch_bounds__(256) void reduce_flag(const float4* __restrict__ pvi,
                                                   const float* __restrict__ pv3,
                                                   int* __restrict__ idxf,
                                                   uint2* __restrict__ pairs,
                                                   int* __restrict__ paircount) {
  const int q = blockIdx.x * 256 + threadIdx.x;
  float4 P[NSLICE];
  float V3[NSLICE];
#pragma unroll
  for (int s = 0; s < NSLICE; ++s) {
    P[s] = pvi[s * NQ + q];
    V3[s] = pv3[s * NQ + q];
  }
  float gv1 = P[0].x;
  int gi1 = __float_as_int(P[0].y);
#pragma unroll
  for (int s = 1; s < NSLICE; ++s) {
    const int oi = __float_as_int(P[s].y);
    if (lexless(P[s].x, oi, gv1, gi1)) { gv1 = P[s].x; gi1 = oi; }
  }
  idxf[q] = gi1;
  const float thr = gv1 + MARGIN;
  int c = 0;
#pragma unroll
  for (int s = 0; s < NSLICE; ++s) c += (P[s].x <= thr) + (P[s].z <= thr);
  if (c <= 1) return;  // unambiguous winner

  int n = 0;
#pragma unroll
  for (int s = 0; s < NSLICE; ++s) {
    if (V3[s] <= thr) n += 1024;
    else n += (P[s].x <= thr) + (P[s].z <= thr);
  }
  int base = atomicAdd(paircount, n);
  if (base + n > CAP_PAIRS) return;
#pragma unroll
  for (int s = 0; s < NSLICE; ++s) {
    if (V3[s] <= thr) {
      for (int j = 0; j < 1024; ++j) pairs[base++] = (uint2){(unsigned)q, (unsigned)(s * 1024 + j)};
    } else {
      if (P[s].x <= thr) pairs[base++] = (uint2){(unsigned)q, (unsigned)__float_as_int(P[s].y)};
      if (P[s].z <= thr) pairs[base++] = (uint2){(unsigned)q, (unsigned)__float_as_int(P[s].w)};
    }
  }
}

// ---------------------------------------------------------------------------
// Exact fp32 rescore of candidate pairs: one wave per (q,k); tie -> min k via
// packed atomicMin. Deterministic fixed-order reduce.
// ---------------------------------------------------------------------------
__global__ __launch_bounds__(256) void exact_cand(const float* __restrict__ z,
                                                  const float* __restrict__ cb,
                                                  const float* __restrict__ cbnorm,
                                                  const float* __restrict__ znorm,
                                                  const uint2* __restrict__ pairs,
                                                  const int* __restrict__ paircount,
                                                  unsigned long long* __restrict__ packed) {
  const int cnt = min(*paircount, CAP_PAIRS);
  const int gw = (blockIdx.x * 256 + threadIdx.x) >> 6;
  const int nw = (gridDim.x * 256) >> 6;
  const int lane = threadIdx.x & 63;
  for (int p = gw; p < cnt; p += nw) {
    const uint2 pr = pairs[p];
    const int q = pr.x, k = pr.y;
    if (q >= NQ || k >= CODES) continue;
    const int b = q >> 10, hw = q & 1023;
    const float* zb = z + b * (FEAT * 1024) + hw;
    const float4 cv = ((const float4*)(cb + (size_t)k * FEAT))[lane];
    const float z0 = zb[(lane * 4 + 0) * 1024];
    const float z1 = zb[(lane * 4 + 1) * 1024];
    const float z2 = zb[(lane * 4 + 2) * 1024];
    const float z3 = zb[(lane * 4 + 3) * 1024];
    float d = __builtin_fmaf(z3, cv.w,
              __builtin_fmaf(z2, cv.z,
              __builtin_fmaf(z1, cv.y, __fmul_rn(z0, cv.x))));
#pragma unroll
    for (int dd = 1; dd < 64; dd <<= 1) d = __fadd_rn(d, __shfl_xor(d, dd, 64));
    const float s = __fadd_rn(__fadd_rn(__fmul_rn(-2.0f, d), znorm[q]), cbnorm[k]);
    if (lane == 0) {
      unsigned u = __float_as_uint(s);
      u = (u & 0x80000000u) ? ~u : (u | 0x80000000u);
      const unsigned long long key = ((unsigned long long)u << 32) | (unsigned)k;
      atomicMin(&packed[q], key);
    }
  }
}

// ---------------------------------------------------------------------------
// Gather: zq[b][c][hw] = cb[idx]; idx (exact overrides approx) as float.
// ---------------------------------------------------------------------------
__global__ __launch_bounds__(256) void vq_gather(const float* __restrict__ cb,
                                                 const unsigned long long* __restrict__ packed,
                                                 const int* __restrict__ idxf,
                                                 float* __restrict__ out) {
  const int q0 = blockIdx.x * 64;
  const int nl = threadIdx.x & 63;
  const int cg = threadIdx.x >> 6;
  const int q = q0 + nl;
  const unsigned long long pk = packed[q];
  const int kq = (pk != ~0ULL) ? (int)(unsigned)pk : idxf[q];
  const int b = q >> 10, hw = q & 1023;
  const float4* cb4 = (const float4*)cb;
#pragma unroll
  for (int t = 0; t < 16; ++t) {
    const int cc = cg + t * 4;
    const float4 v = cb4[kq * 64 + cc];
    const int base = b * (FEAT * 1024) + (cc * 4) * 1024 + hw;
    out[base] = v.x;
    out[base + 1024] = v.y;
    out[base + 2048] = v.z;
    out[base + 3072] = v.w;
  }
  if (threadIdx.x < 64) {
    const int qq = q0 + threadIdx.x;
    const unsigned long long p2 = packed[qq];
    const int k2 = (p2 != ~0ULL) ? (int)(unsigned)p2 : idxf[qq];
    out[ZQ_ELEMS + qq] = (float)k2;
  }
}

extern "C" void kernel_launch(void* const* d_in, const int* in_sizes, int n_in,
                              void* d_out, int out_size, void* d_ws, size_t ws_size,
                              hipStream_t stream) {
  const float* z = (const float*)d_in[0];
  const float* cb = (const float*)d_in[1];
  char* w = (char*)d_ws;
  // ws layout (~19.7 MB)
  char* At = w;                                            // 8 MB
  char* Bt = w + 8388608;                                  // 4 MB
  float4* pvi = (float4*)(w + 12582912);                   // 2 MB
  float* pv3 = (float*)(w + 14680064);                     // 512 KB
  float* cbnorm = (float*)(w + 15204352);                  // 32 KB
  float* znorm = (float*)(w + 15237120);                   // 64 KB
  int* idxf = (int*)(w + 15302656);                        // 64 KB
  int* paircount = (int*)(w + 15368192);                   // 256 B
  unsigned long long* packed = (unsigned long long*)(w + 15368448);  // 128 KB
  uint2* pairs = (uint2*)(w + 15499520);                   // 4 MB

  hipMemsetAsync(paircount, 0, 256, stream);
  hipMemsetAsync(packed, 0xFF, NQ * sizeof(unsigned long long), stream);
  norms_kernel<<<(CODES + NQ) / 16, 256, 0, stream>>>(cb, z, cbnorm, znorm);
  convA<<<1024, 256, 0, stream>>>(z, At);
  convB<<<512, 256, 0, stream>>>(cb, Bt);
  vq_gemm<<<(NQ / 128) * NSLICE, 256, 0, stream>>>(At, Bt, cbnorm, pvi, pv3);
  reduce_flag<<<NQ / 256, 256, 0, stream>>>(pvi, pv3, idxf, pairs, paircount);
  exact_cand<<<256, 256, 0, stream>>>(z, cb, cbnorm, znorm, pairs, paircount, packed);
  vq_gather<<<NQ / 64, 256, 0, stream>>>(cb, packed, idxf, (float*)d_out);
}

// Round 5
// 425.437 us; speedup vs baseline: 2.1965x; 1.0970x over previous
//
#include <hip/hip_runtime.h>
#include <stdint.h>

#define FEAT 256
#define CODES 8192
#define NQ 16384                 // 16*32*32
#define ZQ_ELEMS (NQ * FEAT)
#define MARGIN 2e-3f             // = 2e bound on fp16 score error (R4-validated)
#define NSLICE 8
#define CAP_PAIRS (1 << 17)      // 128K (expected ~18K)

typedef _Float16 f16x8 __attribute__((ext_vector_type(8)));
typedef float f32x4 __attribute__((ext_vector_type(4)));

__device__ __forceinline__ void async_lds16(void* lds, const void* g) {
  __builtin_amdgcn_global_load_lds(
      (const __attribute__((address_space(1))) void*)(uintptr_t)(g),
      (__attribute__((address_space(3))) void*)(uint32_t)(uintptr_t)(lds),
      16, 0, 0);
}

// monotone float<->uint order transform
__device__ __forceinline__ unsigned f2mono(float v) {
  unsigned u = __float_as_uint(v);
  return (u & 0x80000000u) ? ~u : (u | 0x80000000u);
}
__device__ __forceinline__ float mono2f(unsigned t) {
  unsigned u = (t & 0x80000000u) ? (t & 0x7fffffffu) : ~t;
  return __uint_as_float(u);
}

// ---------------------------------------------------------------------------
// numpy pairwise sum-of-squares replication (verified R1-R4, absmax 0).
// ---------------------------------------------------------------------------
template <int STRIDE>
__device__ __forceinline__ float pairwise256_sq(const float* __restrict__ base, int lane16) {
  const int h = lane16 >> 3, j = lane16 & 7;
  const float* p = base + (h * 128 + j) * STRIDE;
  float x = p[0];
  float r = __fmul_rn(x, x);
#pragma unroll
  for (int i = 1; i < 16; ++i) {
    float y = p[i * 8 * STRIDE];
    r = __fadd_rn(r, __fmul_rn(y, y));
  }
  r = __fadd_rn(r, __shfl_xor(r, 1, 64));
  r = __fadd_rn(r, __shfl_xor(r, 2, 64));
  r = __fadd_rn(r, __shfl_xor(r, 4, 64));
  float other = __shfl_xor(r, 8, 64);
  float lo = (h == 0) ? r : other;
  float hi = (h == 0) ? other : r;
  return __fadd_rn(lo, hi);
}

__global__ __launch_bounds__(256) void norms_kernel(const float* __restrict__ cb,
                                                    const float* __restrict__ z,
                                                    float* __restrict__ cbnorm,
                                                    float* __restrict__ znorm) {
  const int g = (blockIdx.x * 256 + threadIdx.x) >> 4;
  const int lane16 = threadIdx.x & 15;
  if (g < CODES) {
    float v = pairwise256_sq<1>(cb + g * FEAT, lane16);
    if (lane16 == 0) cbnorm[g] = v;
  } else {
    const int q = g - CODES;
    const int b = q >> 10, hw = q & 1023;
    float v = pairwise256_sq<1024>(z + b * (FEAT * 1024) + hw, lane16);
    if (lane16 == 0) znorm[q] = v;
  }
}

// ---------------------------------------------------------------------------
// convA: z fp32 -> fp16 tiles [mt][ct][r128][c32] + fp32 transpose zT[q][c]
// ---------------------------------------------------------------------------
__global__ __launch_bounds__(256) void convA(const float* __restrict__ z,
                                             char* __restrict__ At, float* __restrict__ zT) {
  __shared__ _Float16 T[128 * 40];
  __shared__ float Tf[128 * 36];
  const int t = threadIdx.x;
  const int mt = blockIdx.x >> 3, ct = blockIdx.x & 7;
  const int q0 = mt * 128, bb = q0 >> 10, hw0 = q0 & 1023;
  const int c0 = ct * 32;
#pragma unroll
  for (int it = 0; it < 16; ++it) {
    const int cc = it * 2 + (t >> 7);
    const int qi = t & 127;
    float v = z[bb * (FEAT * 1024) + (c0 + cc) * 1024 + hw0 + qi];
    T[qi * 40 + cc] = (_Float16)v;
    Tf[qi * 36 + cc] = v;
  }
  __syncthreads();
  const int r = t >> 1, h = t & 1;
  {
    float4 a = *(const float4*)&T[r * 40 + h * 16];
    float4 b = *(const float4*)&T[r * 40 + h * 16 + 8];
    char* dst = At + (size_t)(mt * 8 + ct) * 8192 + t * 32;
    *(float4*)dst = a;
    *(float4*)(dst + 16) = b;
  }
  float* zrow = zT + (size_t)(q0 + r) * FEAT + c0 + h * 16;
#pragma unroll
  for (int e = 0; e < 4; ++e)
    *(float4*)(zrow + e * 4) = *(const float4*)&Tf[r * 36 + h * 16 + e * 4];
}

// ---------------------------------------------------------------------------
// convB: cb fp32 -> fp16 tiles [nt][ct][n128][c32], scaled by 256
// ---------------------------------------------------------------------------
__global__ __launch_bounds__(256) void convB(const float* __restrict__ cb, char* __restrict__ Bt) {
  const int t = threadIdx.x;
  const int nt = blockIdx.x >> 3, ct = blockIdx.x & 7;
  const int n = t >> 1, h = t & 1;
  const float* src = cb + (size_t)(nt * 128 + n) * FEAT + ct * 32 + h * 16;
  f16x8 o0, o1;
#pragma unroll
  for (int e = 0; e < 8; ++e) o0[e] = (_Float16)(src[e] * 256.0f);
#pragma unroll
  for (int e = 0; e < 8; ++e) o1[e] = (_Float16)(src[8 + e] * 256.0f);
  char* dst = Bt + (size_t)(nt * 8 + ct) * 8192 + t * 32;
  *(f16x8*)dst = o0;
  *(f16x8*)(dst + 16) = o1;
}

// ---------------------------------------------------------------------------
// Shared GEMM body. A-tile (64 KB, all K) resident in LDS; B streams 8 KB
// chunks. PASS=0: per-row running min -> atomicMin gmin[q] (monotone u32).
// PASS=1: push (q<<13|k) for every score <= thr[q] = gmin[q] + MARGIN.
// ---------------------------------------------------------------------------
template <int PASS>
__device__ __forceinline__ void gemm_body(const char* __restrict__ At,
                                          const char* __restrict__ Bt,
                                          const float* __restrict__ cbnorm,
                                          unsigned* __restrict__ gmin,
                                          unsigned* __restrict__ pairs,
                                          int* __restrict__ paircount) {
  __shared__ __align__(16) char Af[65536];
  __shared__ __align__(16) char Bs[8192];
  __shared__ float thrS[128];

  const int tid = threadIdx.x;
  const int slice = blockIdx.x & 7, mt = blockIdx.x >> 3;
  const int wave = tid >> 6, lane = tid & 63;
  const int wm = wave >> 1, wn = wave & 1;
  const int col = lane & 15, quad = lane >> 4;

  const int srow = wave * 32 + (lane >> 2);  // staging row within 32-row group
  const int ss = lane & 3;
  const char* Abase = At + (size_t)(mt * 8) * 8192;

  // stage entire A tile (8 ct-chunks) into LDS, swizzled slots
#pragma unroll
  for (int ct = 0; ct < 8; ++ct) {
#pragma unroll
    for (int i = 0; i < 2; ++i) {
      const int r = srow + i * 16;
      const int cs = ss ^ ((r >> 1) & 3);
      async_lds16(Af + ct * 8192 + wave * 2048 + i * 1024,
                  Abase + (size_t)ct * 8192 + r * 64 + cs * 16);
    }
  }
  if (PASS == 1 && tid < 128) thrS[tid] = mono2f(gmin[mt * 128 + tid]) + MARGIN;

  int aoff[4], boff[4];
#pragma unroll
  for (int i = 0; i < 4; ++i) {
    const int m = wm * 64 + i * 16 + col;
    aoff[i] = m * 64 + ((quad ^ ((m >> 1) & 3)) << 4);
    const int n = wn * 64 + i * 16 + col;
    boff[i] = n * 64 + ((quad ^ ((n >> 1) & 3)) << 4);
  }

  int qrow[16];
#pragma unroll
  for (int row = 0; row < 16; ++row)
    qrow[row] = mt * 128 + wm * 64 + (row >> 2) * 16 + quad * 4 + (row & 3);

  __syncthreads();  // A staged (sync waits vmcnt), thrS ready

  float vmin[16], thr[16];
#pragma unroll
  for (int row = 0; row < 16; ++row) {
    vmin[row] = 3.4e38f;
    thr[row] = (PASS == 1) ? thrS[qrow[row] - mt * 128] : 0.f;
  }

  for (int nt = 0; nt < 8; ++nt) {
    const int ntile = slice * 8 + nt;
    const char* Bbase = Bt + (size_t)(ntile * 8) * 8192;
    f32x4 acc[4][4];
#pragma unroll
    for (int i = 0; i < 4; ++i)
#pragma unroll
      for (int j = 0; j < 4; ++j) acc[i][j] = (f32x4){0.f, 0.f, 0.f, 0.f};

    for (int ct = 0; ct < 8; ++ct) {
      __syncthreads();
#pragma unroll
      for (int i = 0; i < 2; ++i) {
        const int r = srow + i * 16;
        const int cs = ss ^ ((r >> 1) & 3);
        async_lds16(Bs + wave * 2048 + i * 1024, Bbase + (size_t)ct * 8192 + r * 64 + cs * 16);
      }
      __syncthreads();
      f16x8 af[4], bf[4];
#pragma unroll
      for (int i = 0; i < 4; ++i) {
        af[i] = *(const f16x8*)(Af + ct * 8192 + aoff[i]);
        bf[i] = *(const f16x8*)(Bs + boff[i]);
      }
#pragma unroll
      for (int i = 0; i < 4; ++i)
#pragma unroll
        for (int j = 0; j < 4; ++j)
          acc[i][j] = __builtin_amdgcn_mfma_f32_16x16x32_f16(af[i], bf[j], acc[i][j], 0, 0, 0);
    }
    // scoring
    const int k0 = ntile * 128;
#pragma unroll
    for (int j = 0; j < 4; ++j) {
      const int k = k0 + wn * 64 + j * 16 + col;
      const float cn = cbnorm[k];
#pragma unroll
      for (int i = 0; i < 4; ++i)
#pragma unroll
        for (int r = 0; r < 4; ++r) {
          const int row = i * 4 + r;
          const float s = __builtin_fmaf(acc[i][j][r], -0.0078125f, cn);
          if (PASS == 0) {
            vmin[row] = fminf(vmin[row], s);
          } else {
            if (s <= thr[row]) {
              const int slot = atomicAdd(paircount, 1);
              if (slot < CAP_PAIRS) pairs[slot] = ((unsigned)qrow[row] << 13) | (unsigned)k;
            }
          }
        }
    }
  }

  if (PASS == 0) {
    // cross-col min (value only), then atomicMin per row
#pragma unroll
    for (int row = 0; row < 16; ++row) {
      float v = vmin[row];
      v = fminf(v, __shfl_xor(v, 1, 64));
      v = fminf(v, __shfl_xor(v, 2, 64));
      v = fminf(v, __shfl_xor(v, 4, 64));
      v = fminf(v, __shfl_xor(v, 8, 64));
      if (col == 0) atomicMin(&gmin[qrow[row]], f2mono(v));
    }
  }
}

__global__ __launch_bounds__(256, 2) void gemm_pass1(const char* __restrict__ At,
                                                     const char* __restrict__ Bt,
                                                     const float* __restrict__ cbnorm,
                                                     unsigned* __restrict__ gmin) {
  gemm_body<0>(At, Bt, cbnorm, gmin, nullptr, nullptr);
}

__global__ __launch_bounds__(256, 2) void gemm_pass2(const char* __restrict__ At,
                                                     const char* __restrict__ Bt,
                                                     const float* __restrict__ cbnorm,
                                                     unsigned* __restrict__ gmin,
                                                     unsigned* __restrict__ pairs,
                                                     int* __restrict__ paircount) {
  gemm_body<1>(At, Bt, cbnorm, gmin, pairs, paircount);
}

// ---------------------------------------------------------------------------
// Exact fp32 rescore of all pushed pairs (np chain, R4-verified machinery).
// One wave per pair; winner per q via packed atomicMin (ties -> min k).
// ---------------------------------------------------------------------------
__global__ __launch_bounds__(256) void exact_cand(const float* __restrict__ zT,
                                                  const float* __restrict__ cb,
                                                  const float* __restrict__ cbnorm,
                                                  const float* __restrict__ znorm,
                                                  const unsigned* __restrict__ pairs,
                                                  const int* __restrict__ paircount,
                                                  unsigned long long* __restrict__ packed) {
  const int cnt = min(*paircount, CAP_PAIRS);
  const int gw = (blockIdx.x * 256 + threadIdx.x) >> 6;
  const int nw = (gridDim.x * 256) >> 6;
  const int lane = threadIdx.x & 63;
  for (int p = gw; p < cnt; p += nw) {
    const unsigned qk = pairs[p];
    const int q = qk >> 13, k = qk & 8191;
    const float4 cv = ((const float4*)(cb + (size_t)k * FEAT))[lane];
    const float4 zv = ((const float4*)(zT + (size_t)q * FEAT))[lane];
    float d = __builtin_fmaf(zv.w, cv.w,
              __builtin_fmaf(zv.z, cv.z,
              __builtin_fmaf(zv.y, cv.y, __fmul_rn(zv.x, cv.x))));
#pragma unroll
    for (int dd = 1; dd < 64; dd <<= 1) d = __fadd_rn(d, __shfl_xor(d, dd, 64));
    const float s = __fadd_rn(__fadd_rn(__fmul_rn(-2.0f, d), znorm[q]), cbnorm[k]);
    if (lane == 0) {
      const unsigned long long key = ((unsigned long long)f2mono(s) << 32) | (unsigned)k;
      atomicMin(&packed[q], key);
    }
  }
}

// ---------------------------------------------------------------------------
// Gather: zq[b][c][hw] = cb[idx]; idx as float appended after zq.
// ---------------------------------------------------------------------------
__global__ __launch_bounds__(256) void vq_gather(const float* __restrict__ cb,
                                                 const unsigned long long* __restrict__ packed,
                                                 float* __restrict__ out) {
  const int q0 = blockIdx.x * 64;
  const int nl = threadIdx.x & 63;
  const int cg = threadIdx.x >> 6;
  const int q = q0 + nl;
  const int kq = (int)((unsigned)packed[q] & 8191u);
  const int b = q >> 10, hw = q & 1023;
  const float4* cb4 = (const float4*)cb;
#pragma unroll
  for (int t = 0; t < 16; ++t) {
    const int cc = cg + t * 4;
    const float4 v = cb4[kq * 64 + cc];
    const int base = b * (FEAT * 1024) + (cc * 4) * 1024 + hw;
    out[base] = v.x;
    out[base + 1024] = v.y;
    out[base + 2048] = v.z;
    out[base + 3072] = v.w;
  }
  if (threadIdx.x < 64) {
    const int qq = q0 + threadIdx.x;
    out[ZQ_ELEMS + qq] = (float)(int)((unsigned)packed[qq] & 8191u);
  }
}

extern "C" void kernel_launch(void* const* d_in, const int* in_sizes, int n_in,
                              void* d_out, int out_size, void* d_ws, size_t ws_size,
                              hipStream_t stream) {
  const float* z = (const float*)d_in[0];
  const float* cb = (const float*)d_in[1];
  char* w = (char*)d_ws;
  // ws layout (~29.2 MB)
  char* At = w;                                            // 8 MB
  char* Bt = w + 8388608;                                  // 4 MB
  float* zT = (float*)(w + 12582912);                      // 16 MB
  float* cbnorm = (float*)(w + 29360128);                  // 32 KB
  float* znorm = (float*)(w + 29392896);                   // 64 KB
  unsigned* gmin = (unsigned*)(w + 29458432);              // 64 KB
  int* paircount = (int*)(w + 29523968);                   // 256 B
  unsigned* pairs = (unsigned*)(w + 29524224);             // 512 KB
  unsigned long long* packed = (unsigned long long*)(w + 30048512);  // 128 KB

  hipMemsetAsync(paircount, 0, 256, stream);
  hipMemsetAsync(gmin, 0xFF, NQ * sizeof(unsigned), stream);
  hipMemsetAsync(packed, 0xFF, NQ * sizeof(unsigned long long), stream);
  norms_kernel<<<(CODES + NQ) / 16, 256, 0, stream>>>(cb, z, cbnorm, znorm);
  convA<<<1024, 256, 0, stream>>>(z, At, zT);
  convB<<<512, 256, 0, stream>>>(cb, Bt);
  gemm_pass1<<<(NQ / 128) * NSLICE, 256, 0, stream>>>(At, Bt, cbnorm, gmin);
  gemm_pass2<<<(NQ / 128) * NSLICE, 256, 0, stream>>>(At, Bt, cbnorm, gmin, pairs, paircount);
  exact_cand<<<256, 256, 0, stream>>>(zT, cb, cbnorm, znorm, pairs, paircount, packed);
  vq_gather<<<NQ / 64, 256, 0, stream>>>(cb, packed, (float*)d_out);
}